// Round 10
// baseline (461.554 us; speedup 1.0000x reference)
//
#include <hip/hip_runtime.h>
#include <hip/hip_bf16.h>
#include <stdint.h>
#include <stddef.h>

typedef unsigned short u16;
typedef short bf16x8 __attribute__((ext_vector_type(8)));   // 8 bf16 = 4 VGPRs
typedef short bf16x4 __attribute__((ext_vector_type(4)));   // 4 bf16 = 2 VGPRs
typedef float floatx4 __attribute__((ext_vector_type(4)));

#define N_ROWS 8192
#define D_MODEL 1024
#define PROJ 512
#define MHALF 4096          // keys per half-pass (P_half = 8192 x 4096 bf16 = 64 MB)
// exp(S/64) = 2^(S * log2(e)/64)
#define SCALE_LOG2E_DK 0.022542110013890054f

// counted vmcnt wait (T4): immediate must be a literal
#define VMCNT_WAIT(n) asm volatile("s_waitcnt vmcnt(" #n ")" ::: "memory")

#if __has_builtin(__builtin_amdgcn_exp2f)
#define EXP2(x) __builtin_amdgcn_exp2f(x)
#else
#define EXP2(x) exp2f(x)
#endif

__device__ __forceinline__ float bf2f(u16 u) {
    union { unsigned int i; float f; } x; x.i = ((unsigned int)u) << 16; return x.f;
}
__device__ __forceinline__ u16 f2bf(float f) {
    __hip_bfloat16 h = __float2bfloat16(f);   // RNE
    return *reinterpret_cast<u16*>(&h);
}

// async 16B global->LDS. LDS dest = wave-uniform base + lane*16 (m97/m104).
__device__ __forceinline__ void gload_lds16(u16* lds_base, const u16* g) {
    __builtin_amdgcn_global_load_lds(
        (const __attribute__((address_space(1))) void*)g,
        (__attribute__((address_space(3))) void*)lds_base,
        16, 0, 0);
}

// Stage a 128x32 bf16 tile into linear LDS [128][32]; 256 threads, 2 issues each.
__device__ __forceinline__ void stage128x32(u16* lds, const u16* src, int stride,
                                            int wv, int ln) {
    const int rr = ln >> 2;
    const int cc = (ln & 3) << 3;
#pragma unroll
    for (int i = 0; i < 2; ++i) {
        const int rb = i * 64 + wv * 16;
        gload_lds16(lds + rb * 32, src + (size_t)(rb + rr) * stride + cc);
    }
}

// Stage a 256x32 bf16 tile (4 issues per thread).
__device__ __forceinline__ void stage256x32(u16* lds, const u16* src, int stride,
                                            int wv, int ln) {
    const int rr = ln >> 2;
    const int cc = (ln & 3) << 3;
#pragma unroll
    for (int i = 0; i < 4; ++i) {
        const int rb = i * 64 + wv * 16;
        gload_lds16(lds + rb * 32, src + (size_t)(rb + rr) * stride + cc);
    }
}

// ------------------------------------------------- W transpose fp32 -> bf16
__global__ void transpose_w_kernel(const float* __restrict__ in, u16* __restrict__ out,
                                   int R, int C) {
    __shared__ u16 tile[32][33];
    int r = blockIdx.y * 32 + threadIdx.y;
    int c = blockIdx.x * 32 + threadIdx.x;
    tile[threadIdx.y][threadIdx.x] = f2bf(in[(size_t)r * C + c]);
    __syncthreads();
    int ro = blockIdx.x * 32 + threadIdx.y;
    int co = blockIdx.y * 32 + threadIdx.x;
    out[(size_t)ro * R + co] = tile[threadIdx.x][threadIdx.y];
}

// ------------------------------------------------- bf16 transpose (vp->vpT)
// Key axis permuted within each 64-chunk: phys(j) = (j%16)*4 + j/16, matching
// score's packed P-store layout (pv contracts over keys, order-invariant).
__global__ void transpose_kernel(const u16* __restrict__ in, u16* __restrict__ out,
                                 int R, int C) {
    __shared__ u16 tile[32][33];
    int r = blockIdx.y * 32 + threadIdx.y;   // key
    int c = blockIdx.x * 32 + threadIdx.x;   // v-dim
    tile[threadIdx.y][threadIdx.x] = in[(size_t)r * C + c];
    __syncthreads();
    int ro = blockIdx.x * 32 + threadIdx.y;  // v-dim
    int co = blockIdx.y * 32 + threadIdx.x;  // key
    int cp = (co & ~63) | (((co & 15) << 2) + ((co >> 4) & 3));
    out[(size_t)ro * R + cp] = tile[threadIdx.x][threadIdx.y];
}

// ------------------------------------------------- fp32 -> bf16 streaming cvt
__global__ __launch_bounds__(256) void convert_bf16_kernel(
    const float* __restrict__ q, const float* __restrict__ k, const float* __restrict__ v,
    u16* __restrict__ qb, u16* __restrict__ kb, u16* __restrict__ vb)
{
    const float* in = (blockIdx.y == 0) ? q : (blockIdx.y == 1) ? k : v;
    u16* out        = (blockIdx.y == 0) ? qb : (blockIdx.y == 1) ? kb : vb;
    size_t i = ((size_t)blockIdx.x * 256 + threadIdx.x) * 8;
    float4 a = *(const float4*)(in + i);
    float4 b = *(const float4*)(in + i + 4);
    bf16x8 o;
    o[0] = (short)f2bf(a.x); o[1] = (short)f2bf(a.y);
    o[2] = (short)f2bf(a.z); o[3] = (short)f2bf(a.w);
    o[4] = (short)f2bf(b.x); o[5] = (short)f2bf(b.y);
    o[6] = (short)f2bf(b.z); o[7] = (short)f2bf(b.w);
    *(bf16x8*)(out + i) = o;
}

// ---------------------------------------------------------------- projections
// Round-5 form (2-barrier, 16 KB, 128x128, default dispatch) — measured best.
__global__ __launch_bounds__(256) void proj_kernel(
    const u16* __restrict__ qb, const u16* __restrict__ kb, const u16* __restrict__ vb,
    const u16* __restrict__ WqT, const u16* __restrict__ WkT, const u16* __restrict__ WvT,
    const float* __restrict__ bq, const float* __restrict__ bk, const float* __restrict__ bv,
    u16* __restrict__ qp, u16* __restrict__ kp, u16* __restrict__ vp)
{
    const int z = blockIdx.z;
    const u16* A      = (z == 0) ? qb  : (z == 1) ? kb  : vb;
    const u16* WT     = (z == 0) ? WqT : (z == 1) ? WkT : WvT;
    const float* bias = (z == 0) ? bq  : (z == 1) ? bk  : bv;
    u16* C            = (z == 0) ? qp  : (z == 1) ? kp  : vp;

    const int m0 = blockIdx.x * 128;
    const int n0 = blockIdx.y * 128;
    __shared__ __align__(16) u16 smem[2 * 128 * 32];   // 16 KB, linear
    u16* As = smem;
    u16* Bs = smem + 128 * 32;

    const int t = threadIdx.x;
    const int wv = t >> 6, ln = t & 63;
    const int q16 = ln >> 4, l16 = ln & 15;
    const int wm = (wv & 1) * 64, wn = (wv >> 1) * 64;

    floatx4 acc[4][4] = {};

    for (int k0 = 0; k0 < D_MODEL; k0 += 32) {
        __syncthreads();
        stage128x32(As, A  + (size_t)m0 * D_MODEL + k0, D_MODEL, wv, ln);
        stage128x32(Bs, WT + (size_t)n0 * D_MODEL + k0, D_MODEL, wv, ln);
        __syncthreads();

        bf16x8 af[4], bfr[4];
#pragma unroll
        for (int mi = 0; mi < 4; ++mi)
            af[mi] = *(const bf16x8*)(As + (wm + mi * 16 + l16) * 32 + q16 * 8);
#pragma unroll
        for (int ni = 0; ni < 4; ++ni)
            bfr[ni] = *(const bf16x8*)(Bs + (wn + ni * 16 + l16) * 32 + q16 * 8);
#pragma unroll
        for (int mi = 0; mi < 4; ++mi)
#pragma unroll
            for (int ni = 0; ni < 4; ++ni)
                acc[mi][ni] = __builtin_amdgcn_mfma_f32_16x16x32_bf16(
                    af[mi], bfr[ni], acc[mi][ni], 0, 0, 0);
    }

#pragma unroll
    for (int ni = 0; ni < 4; ++ni) {
        int col = n0 + wn + ni * 16 + l16;
        float bv_ = bias[col];
#pragma unroll
        for (int mi = 0; mi < 4; ++mi)
#pragma unroll
            for (int rr = 0; rr < 4; ++rr) {
                int row = m0 + wm + mi * 16 + q16 * 4 + rr;   // C/D layout (m89/m91)
                C[(size_t)row * PROJ + col] = f2bf(acc[mi][ni][rr] + bv_);
            }
    }
}

// ---------------------------------------------------------------- zero l
__global__ void zero_l_kernel(float* __restrict__ l) {
    l[blockIdx.x * 256 + threadIdx.x] = 0.f;
}

// ---------------------------------------------------------------- score pass
// P[8192][4096] = exp2(c * (qp @ kp_h^T)) bf16, l[row] += rowsums (atomic).
// 128x256 tile (MFMA:ds_read 32:12 per K-step vs 16:8 at 128x128), 2-barrier
// 24 KB loop, packed permuted 8B P-stores (two 64-chunks per row per thread).
__global__ __launch_bounds__(256) void score_kernel(
    const u16* __restrict__ qp, const u16* __restrict__ kph,
    u16* __restrict__ P, float* __restrict__ l)
{
    const int m0 = blockIdx.x * 128;
    const int n0 = blockIdx.y * 256;
    __shared__ __align__(16) u16 smem[(128 + 256) * 32];   // 24 KB, linear
    u16* As = smem;                  // 128x32
    u16* Bs = smem + 128 * 32;       // 256x32

    const int t = threadIdx.x;
    const int wv = t >> 6, ln = t & 63;
    const int q16 = ln >> 4, l16 = ln & 15;
    const int wm = (wv & 1) * 64, wn = (wv >> 1) * 128;

    floatx4 acc[4][8] = {};

    for (int k0 = 0; k0 < PROJ; k0 += 32) {
        __syncthreads();
        stage128x32(As, qp  + (size_t)m0 * PROJ + k0, PROJ, wv, ln);
        stage256x32(Bs, kph + (size_t)n0 * PROJ + k0, PROJ, wv, ln);
        __syncthreads();

        bf16x8 af[4], bfr[8];
#pragma unroll
        for (int mi = 0; mi < 4; ++mi)
            af[mi] = *(const bf16x8*)(As + (wm + mi * 16 + l16) * 32 + q16 * 8);
#pragma unroll
        for (int ni = 0; ni < 8; ++ni)
            bfr[ni] = *(const bf16x8*)(Bs + (wn + ni * 16 + l16) * 32 + q16 * 8);
#pragma unroll
        for (int mi = 0; mi < 4; ++mi)
#pragma unroll
            for (int ni = 0; ni < 8; ++ni)
                acc[mi][ni] = __builtin_amdgcn_mfma_f32_16x16x32_bf16(
                    af[mi], bfr[ni], acc[mi][ni], 0, 0, 0);
    }

    // epilogue: exp2, packed permuted store (2 chunks of 64 keys), row-sums.
#pragma unroll
    for (int mi = 0; mi < 4; ++mi)
#pragma unroll
        for (int rr = 0; rr < 4; ++rr) {
            int row = m0 + wm + mi * 16 + q16 * 4 + rr;
            u16* Prow = P + (size_t)row * MHALF + n0 + wn;
            float tot = 0.f;
            bf16x4 pk0, pk1;
#pragma unroll
            for (int ni = 0; ni < 4; ++ni) {
                float x = acc[mi][ni][rr] * SCALE_LOG2E_DK;
                x = fminf(fmaxf(x, -30.f), 30.f);
                float p = EXP2(x);
                tot += p;
                pk0[ni] = (short)f2bf(p);      // chunk 0: key ni*16+l16 -> phys l16*4+ni
            }
#pragma unroll
            for (int ni = 0; ni < 4; ++ni) {
                float x = acc[mi][ni + 4][rr] * SCALE_LOG2E_DK;
                x = fminf(fmaxf(x, -30.f), 30.f);
                float p = EXP2(x);
                tot += p;
                pk1[ni] = (short)f2bf(p);      // chunk 1
            }
            *(bf16x4*)(Prow + l16 * 4)      = pk0;   // 8B coalesced
            *(bf16x4*)(Prow + 64 + l16 * 4) = pk1;   // 8B coalesced
#pragma unroll
            for (int m = 1; m < 16; m <<= 1)
                tot += __shfl_xor(tot, m, 64);
            if (l16 == 0)
                atomicAdd(&l[row], tot);
        }
}

// ---------------------------------------------------------------- PV pass
// Round-5 proven config: 128x128 tile, depth-4 64 KB ring, counted vmcnt
// (8 steady / 4 / 0 peel), grid (64,4,2) default dispatch — 61.6 us measured.
__global__ __launch_bounds__(256) void pv_kernel(
    const u16* __restrict__ P, const u16* __restrict__ vpTh,
    float* __restrict__ Ofull, u16* __restrict__ Opart, int accum)
{
    const int m0 = blockIdx.x * 128;
    const int n0 = blockIdx.y * 128;
    const int kg = blockIdx.z;
    const int kbase = kg * 2048;
    __shared__ __align__(16) u16 smem[4 * 8192];   // 64 KB: ring of 4 x (A 8KB + B 8KB)

    const int t = threadIdx.x;
    const int wv = t >> 6, ln = t & 63;
    const int q16 = ln >> 4, l16 = ln & 15;
    const int wm = (wv & 1) * 64, wn = (wv >> 1) * 64;

    const u16* Abase = P    + (size_t)m0 * MHALF  + kbase;
    const u16* Bbase = vpTh + (size_t)n0 * N_ROWS + kbase;

    floatx4 acc[4][4] = {};

    auto STAGE = [&](int ti) {
        u16* buf = smem + (ti & 3) * 8192;
        stage128x32(buf,        Abase + ti * 32, MHALF,  wv, ln);
        stage128x32(buf + 4096, Bbase + ti * 32, N_ROWS, wv, ln);
    };
    auto COMPUTE = [&](int ti) {
        const u16* As = smem + (ti & 3) * 8192;
        const u16* Bs = As + 4096;
        bf16x8 af[4], bfr[4];
#pragma unroll
        for (int mi = 0; mi < 4; ++mi)
            af[mi] = *(const bf16x8*)(As + (wm + mi * 16 + l16) * 32 + q16 * 8);
#pragma unroll
        for (int ni = 0; ni < 4; ++ni)
            bfr[ni] = *(const bf16x8*)(Bs + (wn + ni * 16 + l16) * 32 + q16 * 8);
#pragma unroll
        for (int mi = 0; mi < 4; ++mi)
#pragma unroll
            for (int ni = 0; ni < 4; ++ni)
                acc[mi][ni] = __builtin_amdgcn_mfma_f32_16x16x32_bf16(
                    af[mi], bfr[ni], acc[mi][ni], 0, 0, 0);
    };

    const int NT = 2048 / 32;   // 64 K-steps
    STAGE(0); STAGE(1); STAGE(2);   // 12 loads/thread in flight

    for (int ti = 0; ti < NT - 2; ++ti) {
        VMCNT_WAIT(8);                          // tile-ti loads landed (12->8)
        __builtin_amdgcn_sched_barrier(0);
        __builtin_amdgcn_s_barrier();           // everyone's landed; reads of ti-1 done
        __builtin_amdgcn_sched_barrier(0);      // pin ds_reads below barrier (rule 18)
        if (ti + 3 < NT) STAGE(ti + 3);         // overwrites slot (ti-1)&3: safe
        COMPUTE(ti);
    }
    VMCNT_WAIT(4);
    __builtin_amdgcn_sched_barrier(0);
    __builtin_amdgcn_s_barrier();
    __builtin_amdgcn_sched_barrier(0);
    COMPUTE(NT - 2);
    VMCNT_WAIT(0);
    __builtin_amdgcn_sched_barrier(0);
    __builtin_amdgcn_s_barrier();
    __builtin_amdgcn_sched_barrier(0);
    COMPUTE(NT - 1);

#pragma unroll
    for (int ni = 0; ni < 4; ++ni) {
        int col = n0 + wn + ni * 16 + l16;
#pragma unroll
        for (int mi = 0; mi < 4; ++mi)
#pragma unroll
            for (int rr = 0; rr < 4; ++rr) {
                int row = m0 + wm + mi * 16 + q16 * 4 + rr;
                size_t o = (size_t)row * PROJ + col;
                float v = acc[mi][ni][rr];
                if (kg == 0) {
                    if (accum) v += Ofull[o];
                    Ofull[o] = v;
                } else {
                    if (accum) v += bf2f(Opart[o]);
                    Opart[o] = f2bf(v);
                }
            }
    }
}

// ---------------------------------------------------------------- scale
__global__ void scale_kernel(float* __restrict__ out, const u16* __restrict__ Opart,
                             const float* __restrict__ l)
{
    int idx = blockIdx.x * 256 + threadIdx.x;   // 8192*512
    int row = idx >> 9;
    out[idx] = (out[idx] + bf2f(Opart[idx])) / l[row];
}

// ---------------------------------------------------------------- launch
extern "C" void kernel_launch(void* const* d_in, const int* in_sizes, int n_in,
                              void* d_out, int out_size, void* d_ws, size_t ws_size,
                              hipStream_t stream)
{
    (void)in_sizes; (void)n_in; (void)out_size;
    if (ws_size < ((size_t)101 << 20)) return;   // visible-fail guard

    const float* q  = (const float*)d_in[0];
    const float* k  = (const float*)d_in[1];
    const float* v  = (const float*)d_in[2];
    const float* Wq = (const float*)d_in[3];
    const float* bq = (const float*)d_in[4];
    const float* Wk = (const float*)d_in[5];
    const float* bk = (const float*)d_in[6];
    const float* Wv = (const float*)d_in[7];
    const float* bv = (const float*)d_in[8];

    char* ws = (char*)d_ws;
    u16* qp    = (u16*)(ws);                        // 8 MB
    u16* kp    = (u16*)(ws + ((size_t)8  << 20));   // 8 MB
    u16* vp    = (u16*)(ws + ((size_t)16 << 20));   // 8 MB (dead after vpT -> reused as Opart)
    u16* vpT   = (u16*)(ws + ((size_t)24 << 20));   // 8 MB
    u16* WqT   = (u16*)(ws + ((size_t)32 << 20));   // 1 MB each (bf16 512x1024)
    u16* WkT   = (u16*)(ws + ((size_t)33 << 20));
    u16* WvT   = (u16*)(ws + ((size_t)34 << 20));
    float* l   = (float*)(ws + ((size_t)35 << 20)); // 32 KB
    u16* P     = (u16*)(ws + ((size_t)36 << 20));   // 64 MB (half-P, reused per half)
    // bf16 copies of q,k,v live in the P region (dead once proj is done; score
    // then overwrites P). 16 MB each.
    u16* qb    = (u16*)(ws + ((size_t)36 << 20));
    u16* kb    = (u16*)(ws + ((size_t)52 << 20));
    u16* vb    = (u16*)(ws + ((size_t)68 << 20));
    u16* Opart = vp;                                // kg1 partial, bf16 8 MB
    float* Ofull = (float*)d_out;                   // kg0 partial accumulates in d_out

    dim3 tb(32, 32);
    transpose_w_kernel<<<dim3(16, 32), tb, 0, stream>>>(Wq, WqT, 1024, 512);
    transpose_w_kernel<<<dim3(16, 32), tb, 0, stream>>>(Wk, WkT, 1024, 512);
    transpose_w_kernel<<<dim3(16, 32), tb, 0, stream>>>(Wv, WvT, 1024, 512);

    convert_bf16_kernel<<<dim3(4096, 3), 256, 0, stream>>>(q, k, v, qb, kb, vb);

    proj_kernel<<<dim3(64, 4, 3), 256, 0, stream>>>(qb, kb, vb, WqT, WkT, WvT,
                                                    bq, bk, bv, qp, kp, vp);

    transpose_kernel<<<dim3(16, 256), tb, 0, stream>>>(vp, vpT, 8192, 512);

    zero_l_kernel<<<32, 256, 0, stream>>>(l);

    // half 0
    score_kernel<<<dim3(64, 16), 256, 0, stream>>>(qp, kp, P, l);
    pv_kernel<<<dim3(64, 4, 2), 256, 0, stream>>>(P, vpT, Ofull, Opart, 0);
    // half 1
    score_kernel<<<dim3(64, 16), 256, 0, stream>>>(qp, kp + (size_t)MHALF * PROJ, P, l);
    pv_kernel<<<dim3(64, 4, 2), 256, 0, stream>>>(P, vpT + MHALF, Ofull, Opart, 1);

    scale_kernel<<<16384, 256, 0, stream>>>(Ofull, Opart, l);
}

// Round 11
// 402.613 us; speedup vs baseline: 1.1464x; 1.1464x over previous
//
#include <hip/hip_runtime.h>
#include <hip/hip_bf16.h>
#include <stdint.h>
#include <stddef.h>

typedef unsigned short u16;
typedef short bf16x8 __attribute__((ext_vector_type(8)));   // 8 bf16 = 4 VGPRs
typedef short bf16x4 __attribute__((ext_vector_type(4)));   // 4 bf16 = 2 VGPRs
typedef float floatx4 __attribute__((ext_vector_type(4)));

#define N_ROWS 8192
#define D_MODEL 1024
#define PROJ 512
#define MHALF 4096          // keys per half-pass (P_half = 8192 x 4096 bf16 = 64 MB)
// exp(S/64) = 2^(S * log2(e)/64)
#define SCALE_LOG2E_DK 0.022542110013890054f

// counted vmcnt wait (T4): immediate must be a literal
#define VMCNT_WAIT(n) asm volatile("s_waitcnt vmcnt(" #n ")" ::: "memory")

#if __has_builtin(__builtin_amdgcn_exp2f)
#define EXP2(x) __builtin_amdgcn_exp2f(x)
#else
#define EXP2(x) exp2f(x)
#endif

__device__ __forceinline__ float bf2f(u16 u) {
    union { unsigned int i; float f; } x; x.i = ((unsigned int)u) << 16; return x.f;
}
__device__ __forceinline__ u16 f2bf(float f) {
    __hip_bfloat16 h = __float2bfloat16(f);   // RNE
    return *reinterpret_cast<u16*>(&h);
}

// async 16B global->LDS. LDS dest = wave-uniform base + lane*16 (m97/m104).
__device__ __forceinline__ void gload_lds16(u16* lds_base, const u16* g) {
    __builtin_amdgcn_global_load_lds(
        (const __attribute__((address_space(1))) void*)g,
        (__attribute__((address_space(3))) void*)lds_base,
        16, 0, 0);
}

// Stage a 128x32 bf16 tile into linear LDS [128][32]; 256 threads, 2 issues each.
__device__ __forceinline__ void stage128x32(u16* lds, const u16* src, int stride,
                                            int wv, int ln) {
    const int rr = ln >> 2;
    const int cc = (ln & 3) << 3;
#pragma unroll
    for (int i = 0; i < 2; ++i) {
        const int rb = i * 64 + wv * 16;
        gload_lds16(lds + rb * 32, src + (size_t)(rb + rr) * stride + cc);
    }
}

// ------------------------------------------------- W transpose fp32 -> bf16
__global__ void transpose_w_kernel(const float* __restrict__ in, u16* __restrict__ out,
                                   int R, int C) {
    __shared__ u16 tile[32][33];
    int r = blockIdx.y * 32 + threadIdx.y;
    int c = blockIdx.x * 32 + threadIdx.x;
    tile[threadIdx.y][threadIdx.x] = f2bf(in[(size_t)r * C + c]);
    __syncthreads();
    int ro = blockIdx.x * 32 + threadIdx.y;
    int co = blockIdx.y * 32 + threadIdx.x;
    out[(size_t)ro * R + co] = tile[threadIdx.x][threadIdx.y];
}

// ------------------------------------------------- bf16 transpose (vp->vpT)
// Key axis permuted within each 64-chunk: phys(j) = (j%16)*4 + j/16, matching
// score's packed P-store layout (pv contracts over keys, order-invariant).
__global__ void transpose_kernel(const u16* __restrict__ in, u16* __restrict__ out,
                                 int R, int C) {
    __shared__ u16 tile[32][33];
    int r = blockIdx.y * 32 + threadIdx.y;   // key
    int c = blockIdx.x * 32 + threadIdx.x;   // v-dim
    tile[threadIdx.y][threadIdx.x] = in[(size_t)r * C + c];
    __syncthreads();
    int ro = blockIdx.x * 32 + threadIdx.y;  // v-dim
    int co = blockIdx.y * 32 + threadIdx.x;  // key
    int cp = (co & ~63) | (((co & 15) << 2) + ((co >> 4) & 3));
    out[(size_t)ro * R + cp] = tile[threadIdx.x][threadIdx.y];
}

// ------------------------------------------------- fp32 -> bf16 streaming cvt
__global__ __launch_bounds__(256) void convert_bf16_kernel(
    const float* __restrict__ q, const float* __restrict__ k, const float* __restrict__ v,
    u16* __restrict__ qb, u16* __restrict__ kb, u16* __restrict__ vb)
{
    const float* in = (blockIdx.y == 0) ? q : (blockIdx.y == 1) ? k : v;
    u16* out        = (blockIdx.y == 0) ? qb : (blockIdx.y == 1) ? kb : vb;
    size_t i = ((size_t)blockIdx.x * 256 + threadIdx.x) * 8;
    float4 a = *(const float4*)(in + i);
    float4 b = *(const float4*)(in + i + 4);
    bf16x8 o;
    o[0] = (short)f2bf(a.x); o[1] = (short)f2bf(a.y);
    o[2] = (short)f2bf(a.z); o[3] = (short)f2bf(a.w);
    o[4] = (short)f2bf(b.x); o[5] = (short)f2bf(b.y);
    o[6] = (short)f2bf(b.z); o[7] = (short)f2bf(b.w);
    *(bf16x8*)(out + i) = o;
}

// ---------------------------------------------------------------- projections
// Round-5 form (2-barrier, 16 KB, 128x128, default dispatch) — measured best.
__global__ __launch_bounds__(256) void proj_kernel(
    const u16* __restrict__ qb, const u16* __restrict__ kb, const u16* __restrict__ vb,
    const u16* __restrict__ WqT, const u16* __restrict__ WkT, const u16* __restrict__ WvT,
    const float* __restrict__ bq, const float* __restrict__ bk, const float* __restrict__ bv,
    u16* __restrict__ qp, u16* __restrict__ kp, u16* __restrict__ vp)
{
    const int z = blockIdx.z;
    const u16* A      = (z == 0) ? qb  : (z == 1) ? kb  : vb;
    const u16* WT     = (z == 0) ? WqT : (z == 1) ? WkT : WvT;
    const float* bias = (z == 0) ? bq  : (z == 1) ? bk  : bv;
    u16* C            = (z == 0) ? qp  : (z == 1) ? kp  : vp;

    const int m0 = blockIdx.x * 128;
    const int n0 = blockIdx.y * 128;
    __shared__ __align__(16) u16 smem[2 * 128 * 32];   // 16 KB, linear
    u16* As = smem;
    u16* Bs = smem + 128 * 32;

    const int t = threadIdx.x;
    const int wv = t >> 6, ln = t & 63;
    const int q16 = ln >> 4, l16 = ln & 15;
    const int wm = (wv & 1) * 64, wn = (wv >> 1) * 64;

    floatx4 acc[4][4] = {};

    for (int k0 = 0; k0 < D_MODEL; k0 += 32) {
        __syncthreads();
        stage128x32(As, A  + (size_t)m0 * D_MODEL + k0, D_MODEL, wv, ln);
        stage128x32(Bs, WT + (size_t)n0 * D_MODEL + k0, D_MODEL, wv, ln);
        __syncthreads();

        bf16x8 af[4], bfr[4];
#pragma unroll
        for (int mi = 0; mi < 4; ++mi)
            af[mi] = *(const bf16x8*)(As + (wm + mi * 16 + l16) * 32 + q16 * 8);
#pragma unroll
        for (int ni = 0; ni < 4; ++ni)
            bfr[ni] = *(const bf16x8*)(Bs + (wn + ni * 16 + l16) * 32 + q16 * 8);
#pragma unroll
        for (int mi = 0; mi < 4; ++mi)
#pragma unroll
            for (int ni = 0; ni < 4; ++ni)
                acc[mi][ni] = __builtin_amdgcn_mfma_f32_16x16x32_bf16(
                    af[mi], bfr[ni], acc[mi][ni], 0, 0, 0);
    }

#pragma unroll
    for (int ni = 0; ni < 4; ++ni) {
        int col = n0 + wn + ni * 16 + l16;
        float bv_ = bias[col];
#pragma unroll
        for (int mi = 0; mi < 4; ++mi)
#pragma unroll
            for (int rr = 0; rr < 4; ++rr) {
                int row = m0 + wm + mi * 16 + q16 * 4 + rr;   // C/D layout (m89/m91)
                C[(size_t)row * PROJ + col] = f2bf(acc[mi][ni][rr] + bv_);
            }
    }
}

// ---------------------------------------------------------------- zero l
__global__ void zero_l_kernel(float* __restrict__ l) {
    l[blockIdx.x * 256 + threadIdx.x] = 0.f;
}

// ---------------------------------------------------------------- score pass
// P[8192][4096] = exp2(c * (qp @ kp_h^T)) bf16, l[row] += rowsums (atomic).
// Round-6 proven config: 128x128 tile, 2-barrier 16 KB loop (occupancy-fed),
// packed permuted 8B P-stores. 128x256 regressed (VGPR 164 -> occupancy loss).
__global__ __launch_bounds__(256) void score_kernel(
    const u16* __restrict__ qp, const u16* __restrict__ kph,
    u16* __restrict__ P, float* __restrict__ l)
{
    const int m0 = blockIdx.x * 128;
    const int n0 = blockIdx.y * 128;
    __shared__ __align__(16) u16 smem[2 * 128 * 32];   // 16 KB, linear
    u16* As = smem;
    u16* Bs = smem + 128 * 32;

    const int t = threadIdx.x;
    const int wv = t >> 6, ln = t & 63;
    const int q16 = ln >> 4, l16 = ln & 15;
    const int wm = (wv & 1) * 64, wn = (wv >> 1) * 64;

    floatx4 acc[4][4] = {};

    for (int k0 = 0; k0 < PROJ; k0 += 32) {
        __syncthreads();
        stage128x32(As, qp  + (size_t)m0 * PROJ + k0, PROJ, wv, ln);
        stage128x32(Bs, kph + (size_t)n0 * PROJ + k0, PROJ, wv, ln);
        __syncthreads();

        bf16x8 af[4], bfr[4];
#pragma unroll
        for (int mi = 0; mi < 4; ++mi)
            af[mi] = *(const bf16x8*)(As + (wm + mi * 16 + l16) * 32 + q16 * 8);
#pragma unroll
        for (int ni = 0; ni < 4; ++ni)
            bfr[ni] = *(const bf16x8*)(Bs + (wn + ni * 16 + l16) * 32 + q16 * 8);
#pragma unroll
        for (int mi = 0; mi < 4; ++mi)
#pragma unroll
            for (int ni = 0; ni < 4; ++ni)
                acc[mi][ni] = __builtin_amdgcn_mfma_f32_16x16x32_bf16(
                    af[mi], bfr[ni], acc[mi][ni], 0, 0, 0);
    }

    // epilogue: exp2, packed permuted store, fused row-sums -> atomicAdd l
#pragma unroll
    for (int mi = 0; mi < 4; ++mi)
#pragma unroll
        for (int rr = 0; rr < 4; ++rr) {
            int row = m0 + wm + mi * 16 + q16 * 4 + rr;
            u16* Prow = P + (size_t)row * MHALF + n0 + wn;
            float tot = 0.f;
            bf16x4 pk;
#pragma unroll
            for (int ni = 0; ni < 4; ++ni) {
                float x = acc[mi][ni][rr] * SCALE_LOG2E_DK;
                x = fminf(fmaxf(x, -30.f), 30.f);
                float p = EXP2(x);
                tot += p;
                pk[ni] = (short)f2bf(p);   // key ni*16+l16 -> phys l16*4+ni
            }
            *(bf16x4*)(Prow + l16 * 4) = pk;   // 8B coalesced
#pragma unroll
            for (int m = 1; m < 16; m <<= 1)
                tot += __shfl_xor(tot, m, 64);
            if (l16 == 0)
                atomicAdd(&l[row], tot);
        }
}

// ---------------------------------------------------------------- PV pass
// O += P[8192][4096] @ V_h (both key axes carry the within-64 permutation).
// 128x128 tile, depth-3 ring (48 KB -> 3 blocks/CU), counted vmcnt
// (4 steady / 0 peel), grid (64,4,2) default dispatch. Same tile geometry as
// the 61.6 us depth-4 version (FETCH must stay ~62 MB) — tests whether
// inter-block overlap stacks with the counted-vmcnt pipeline.
__global__ __launch_bounds__(256) void pv_kernel(
    const u16* __restrict__ P, const u16* __restrict__ vpTh,
    float* __restrict__ Ofull, u16* __restrict__ Opart, int accum)
{
    const int m0 = blockIdx.x * 128;
    const int n0 = blockIdx.y * 128;
    const int kg = blockIdx.z;
    const int kbase = kg * 2048;
    __shared__ __align__(16) u16 smem[3 * 8192];   // 48 KB: ring of 3 x (A 8KB + B 8KB)

    const int t = threadIdx.x;
    const int wv = t >> 6, ln = t & 63;
    const int q16 = ln >> 4, l16 = ln & 15;
    const int wm = (wv & 1) * 64, wn = (wv >> 1) * 64;

    const u16* Abase = P    + (size_t)m0 * MHALF  + kbase;
    const u16* Bbase = vpTh + (size_t)n0 * N_ROWS + kbase;

    floatx4 acc[4][4] = {};

    auto STAGE = [&](int ti) {
        u16* buf = smem + (ti % 3) * 8192;
        stage128x32(buf,        Abase + ti * 32, MHALF,  wv, ln);
        stage128x32(buf + 4096, Bbase + ti * 32, N_ROWS, wv, ln);
    };
    auto COMPUTE = [&](int ti) {
        const u16* As = smem + (ti % 3) * 8192;
        const u16* Bs = As + 4096;
        bf16x8 af[4], bfr[4];
#pragma unroll
        for (int mi = 0; mi < 4; ++mi)
            af[mi] = *(const bf16x8*)(As + (wm + mi * 16 + l16) * 32 + q16 * 8);
#pragma unroll
        for (int ni = 0; ni < 4; ++ni)
            bfr[ni] = *(const bf16x8*)(Bs + (wn + ni * 16 + l16) * 32 + q16 * 8);
#pragma unroll
        for (int mi = 0; mi < 4; ++mi)
#pragma unroll
            for (int ni = 0; ni < 4; ++ni)
                acc[mi][ni] = __builtin_amdgcn_mfma_f32_16x16x32_bf16(
                    af[mi], bfr[ni], acc[mi][ni], 0, 0, 0);
    };

    const int NT = 2048 / 32;   // 64 K-steps
    STAGE(0); STAGE(1);         // 8 loads/thread in flight (2 tiles)

    for (int ti = 0; ti < NT - 1; ++ti) {
        VMCNT_WAIT(4);                          // tile-ti loads landed (8->4)
        __builtin_amdgcn_sched_barrier(0);
        __builtin_amdgcn_s_barrier();           // all waves' reads of ti-1 done
        __builtin_amdgcn_sched_barrier(0);      // pin ds_reads below barrier (rule 18)
        if (ti + 2 < NT) STAGE(ti + 2);         // overwrites slot (ti-1)%3: safe
        COMPUTE(ti);
    }
    VMCNT_WAIT(0);
    __builtin_amdgcn_sched_barrier(0);
    __builtin_amdgcn_s_barrier();
    __builtin_amdgcn_sched_barrier(0);
    COMPUTE(NT - 1);

#pragma unroll
    for (int ni = 0; ni < 4; ++ni) {
        int col = n0 + wn + ni * 16 + l16;
#pragma unroll
        for (int mi = 0; mi < 4; ++mi)
#pragma unroll
            for (int rr = 0; rr < 4; ++rr) {
                int row = m0 + wm + mi * 16 + q16 * 4 + rr;
                size_t o = (size_t)row * PROJ + col;
                float v = acc[mi][ni][rr];
                if (kg == 0) {
                    if (accum) v += Ofull[o];
                    Ofull[o] = v;
                } else {
                    if (accum) v += bf2f(Opart[o]);
                    Opart[o] = f2bf(v);
                }
            }
    }
}

// ---------------------------------------------------------------- scale
__global__ void scale_kernel(float* __restrict__ out, const u16* __restrict__ Opart,
                             const float* __restrict__ l)
{
    int idx = blockIdx.x * 256 + threadIdx.x;   // 8192*512
    int row = idx >> 9;
    out[idx] = (out[idx] + bf2f(Opart[idx])) / l[row];
}

// ---------------------------------------------------------------- launch
extern "C" void kernel_launch(void* const* d_in, const int* in_sizes, int n_in,
                              void* d_out, int out_size, void* d_ws, size_t ws_size,
                              hipStream_t stream)
{
    (void)in_sizes; (void)n_in; (void)out_size;
    if (ws_size < ((size_t)101 << 20)) return;   // visible-fail guard

    const float* q  = (const float*)d_in[0];
    const float* k  = (const float*)d_in[1];
    const float* v  = (const float*)d_in[2];
    const float* Wq = (const float*)d_in[3];
    const float* bq = (const float*)d_in[4];
    const float* Wk = (const float*)d_in[5];
    const float* bk = (const float*)d_in[6];
    const float* Wv = (const float*)d_in[7];
    const float* bv = (const float*)d_in[8];

    char* ws = (char*)d_ws;
    u16* qp    = (u16*)(ws);                        // 8 MB
    u16* kp    = (u16*)(ws + ((size_t)8  << 20));   // 8 MB
    u16* vp    = (u16*)(ws + ((size_t)16 << 20));   // 8 MB (dead after vpT -> reused as Opart)
    u16* vpT   = (u16*)(ws + ((size_t)24 << 20));   // 8 MB
    u16* WqT   = (u16*)(ws + ((size_t)32 << 20));   // 1 MB each (bf16 512x1024)
    u16* WkT   = (u16*)(ws + ((size_t)33 << 20));
    u16* WvT   = (u16*)(ws + ((size_t)34 << 20));
    float* l   = (float*)(ws + ((size_t)35 << 20)); // 32 KB
    u16* P     = (u16*)(ws + ((size_t)36 << 20));   // 64 MB (half-P, reused per half)
    // bf16 copies of q,k,v live in the P region (dead once proj is done; score
    // then overwrites P). 16 MB each.
    u16* qb    = (u16*)(ws + ((size_t)36 << 20));
    u16* kb    = (u16*)(ws + ((size_t)52 << 20));
    u16* vb    = (u16*)(ws + ((size_t)68 << 20));
    u16* Opart = vp;                                // kg1 partial, bf16 8 MB
    float* Ofull = (float*)d_out;                   // kg0 partial accumulates in d_out

    dim3 tb(32, 32);
    transpose_w_kernel<<<dim3(16, 32), tb, 0, stream>>>(Wq, WqT, 1024, 512);
    transpose_w_kernel<<<dim3(16, 32), tb, 0, stream>>>(Wk, WkT, 1024, 512);
    transpose_w_kernel<<<dim3(16, 32), tb, 0, stream>>>(Wv, WvT, 1024, 512);

    convert_bf16_kernel<<<dim3(4096, 3), 256, 0, stream>>>(q, k, v, qb, kb, vb);

    proj_kernel<<<dim3(64, 4, 3), 256, 0, stream>>>(qb, kb, vb, WqT, WkT, WvT,
                                                    bq, bk, bv, qp, kp, vp);

    transpose_kernel<<<dim3(16, 256), tb, 0, stream>>>(vp, vpT, 8192, 512);

    zero_l_kernel<<<32, 256, 0, stream>>>(l);

    // half 0
    score_kernel<<<dim3(64, 32), 256, 0, stream>>>(qp, kp, P, l);
    pv_kernel<<<dim3(64, 4, 2), 256, 0, stream>>>(P, vpT, Ofull, Opart, 0);
    // half 1
    score_kernel<<<dim3(64, 32), 256, 0, stream>>>(qp, kp + (size_t)MHALF * PROJ, P, l);
    pv_kernel<<<dim3(64, 4, 2), 256, 0, stream>>>(P, vpT + MHALF, Ofull, Opart, 1);

    scale_kernel<<<16384, 256, 0, stream>>>(Ofull, Opart, l);
}

// Round 12
// 394.239 us; speedup vs baseline: 1.1707x; 1.0212x over previous
//
#include <hip/hip_runtime.h>
#include <hip/hip_bf16.h>
#include <stdint.h>
#include <stddef.h>

typedef unsigned short u16;
typedef short bf16x8 __attribute__((ext_vector_type(8)));   // 8 bf16 = 4 VGPRs
typedef short bf16x4 __attribute__((ext_vector_type(4)));   // 4 bf16 = 2 VGPRs
typedef float floatx4 __attribute__((ext_vector_type(4)));

#define N_ROWS 8192
#define D_MODEL 1024
#define PROJ 512
#define MHALF 4096          // keys per half-pass (P_half = 8192 x 4096 bf16 = 64 MB)
// exp(S/64) = 2^(S * log2(e)/64)
#define SCALE_LOG2E_DK 0.022542110013890054f

// counted vmcnt wait (T4): immediate must be a literal
#define VMCNT_WAIT(n) asm volatile("s_waitcnt vmcnt(" #n ")" ::: "memory")

#if __has_builtin(__builtin_amdgcn_exp2f)
#define EXP2(x) __builtin_amdgcn_exp2f(x)
#else
#define EXP2(x) exp2f(x)
#endif

__device__ __forceinline__ float bf2f(u16 u) {
    union { unsigned int i; float f; } x; x.i = ((unsigned int)u) << 16; return x.f;
}
__device__ __forceinline__ u16 f2bf(float f) {
    __hip_bfloat16 h = __float2bfloat16(f);   // RNE
    return *reinterpret_cast<u16*>(&h);
}

// async 16B global->LDS. LDS dest = wave-uniform base + lane*16 (m97/m104).
__device__ __forceinline__ void gload_lds16(u16* lds_base, const u16* g) {
    __builtin_amdgcn_global_load_lds(
        (const __attribute__((address_space(1))) void*)g,
        (__attribute__((address_space(3))) void*)lds_base,
        16, 0, 0);
}

// Stage a 128x32 bf16 tile into linear LDS [128][32]; 256 threads, 2 issues each.
__device__ __forceinline__ void stage128x32(u16* lds, const u16* src, int stride,
                                            int wv, int ln) {
    const int rr = ln >> 2;
    const int cc = (ln & 3) << 3;
#pragma unroll
    for (int i = 0; i < 2; ++i) {
        const int rb = i * 64 + wv * 16;
        gload_lds16(lds + rb * 32, src + (size_t)(rb + rr) * stride + cc);
    }
}

// Stage a 256x32 bf16 tile with 512 threads (8 waves), 2 issues each.
// LDS linear [256][32]: thread (w,l) round i -> rows i*128 + w*16 + l/4.
__device__ __forceinline__ void stage256x32w(u16* lds, const u16* src, int stride,
                                             int w, int ln) {
    const int rr = ln >> 2;
    const int cc = (ln & 3) << 3;
#pragma unroll
    for (int i = 0; i < 2; ++i) {
        const int rb = i * 128 + w * 16;
        gload_lds16(lds + rb * 32, src + (size_t)(rb + rr) * stride + cc);
    }
}

// ------------------------------------------------- W transpose fp32 -> bf16
__global__ void transpose_w_kernel(const float* __restrict__ in, u16* __restrict__ out,
                                   int R, int C) {
    __shared__ u16 tile[32][33];
    int r = blockIdx.y * 32 + threadIdx.y;
    int c = blockIdx.x * 32 + threadIdx.x;
    tile[threadIdx.y][threadIdx.x] = f2bf(in[(size_t)r * C + c]);
    __syncthreads();
    int ro = blockIdx.x * 32 + threadIdx.y;
    int co = blockIdx.y * 32 + threadIdx.x;
    out[(size_t)ro * R + co] = tile[threadIdx.x][threadIdx.y];
}

// ------------------------------------------------- bf16 transpose (vp->vpT)
// Key axis permuted within each 64-chunk: phys(j) = (j%16)*4 + j/16, matching
// score's packed P-store layout (pv contracts over keys, order-invariant).
__global__ void transpose_kernel(const u16* __restrict__ in, u16* __restrict__ out,
                                 int R, int C) {
    __shared__ u16 tile[32][33];
    int r = blockIdx.y * 32 + threadIdx.y;   // key
    int c = blockIdx.x * 32 + threadIdx.x;   // v-dim
    tile[threadIdx.y][threadIdx.x] = in[(size_t)r * C + c];
    __syncthreads();
    int ro = blockIdx.x * 32 + threadIdx.y;  // v-dim
    int co = blockIdx.y * 32 + threadIdx.x;  // key
    int cp = (co & ~63) | (((co & 15) << 2) + ((co >> 4) & 3));
    out[(size_t)ro * R + cp] = tile[threadIdx.x][threadIdx.y];
}

// ------------------------------------------------- fp32 -> bf16 streaming cvt
__global__ __launch_bounds__(256) void convert_bf16_kernel(
    const float* __restrict__ q, const float* __restrict__ k, const float* __restrict__ v,
    u16* __restrict__ qb, u16* __restrict__ kb, u16* __restrict__ vb)
{
    const float* in = (blockIdx.y == 0) ? q : (blockIdx.y == 1) ? k : v;
    u16* out        = (blockIdx.y == 0) ? qb : (blockIdx.y == 1) ? kb : vb;
    size_t i = ((size_t)blockIdx.x * 256 + threadIdx.x) * 8;
    float4 a = *(const float4*)(in + i);
    float4 b = *(const float4*)(in + i + 4);
    bf16x8 o;
    o[0] = (short)f2bf(a.x); o[1] = (short)f2bf(a.y);
    o[2] = (short)f2bf(a.z); o[3] = (short)f2bf(a.w);
    o[4] = (short)f2bf(b.x); o[5] = (short)f2bf(b.y);
    o[6] = (short)f2bf(b.z); o[7] = (short)f2bf(b.w);
    *(bf16x8*)(out + i) = o;
}

// ---------------------------------------------------------------- projections
// Round-5 form (2-barrier, 16 KB, 128x128, default dispatch) — measured best.
__global__ __launch_bounds__(256) void proj_kernel(
    const u16* __restrict__ qb, const u16* __restrict__ kb, const u16* __restrict__ vb,
    const u16* __restrict__ WqT, const u16* __restrict__ WkT, const u16* __restrict__ WvT,
    const float* __restrict__ bq, const float* __restrict__ bk, const float* __restrict__ bv,
    u16* __restrict__ qp, u16* __restrict__ kp, u16* __restrict__ vp)
{
    const int z = blockIdx.z;
    const u16* A      = (z == 0) ? qb  : (z == 1) ? kb  : vb;
    const u16* WT     = (z == 0) ? WqT : (z == 1) ? WkT : WvT;
    const float* bias = (z == 0) ? bq  : (z == 1) ? bk  : bv;
    u16* C            = (z == 0) ? qp  : (z == 1) ? kp  : vp;

    const int m0 = blockIdx.x * 128;
    const int n0 = blockIdx.y * 128;
    __shared__ __align__(16) u16 smem[2 * 128 * 32];   // 16 KB, linear
    u16* As = smem;
    u16* Bs = smem + 128 * 32;

    const int t = threadIdx.x;
    const int wv = t >> 6, ln = t & 63;
    const int q16 = ln >> 4, l16 = ln & 15;
    const int wm = (wv & 1) * 64, wn = (wv >> 1) * 64;

    floatx4 acc[4][4] = {};

    for (int k0 = 0; k0 < D_MODEL; k0 += 32) {
        __syncthreads();
        stage128x32(As, A  + (size_t)m0 * D_MODEL + k0, D_MODEL, wv, ln);
        stage128x32(Bs, WT + (size_t)n0 * D_MODEL + k0, D_MODEL, wv, ln);
        __syncthreads();

        bf16x8 af[4], bfr[4];
#pragma unroll
        for (int mi = 0; mi < 4; ++mi)
            af[mi] = *(const bf16x8*)(As + (wm + mi * 16 + l16) * 32 + q16 * 8);
#pragma unroll
        for (int ni = 0; ni < 4; ++ni)
            bfr[ni] = *(const bf16x8*)(Bs + (wn + ni * 16 + l16) * 32 + q16 * 8);
#pragma unroll
        for (int mi = 0; mi < 4; ++mi)
#pragma unroll
            for (int ni = 0; ni < 4; ++ni)
                acc[mi][ni] = __builtin_amdgcn_mfma_f32_16x16x32_bf16(
                    af[mi], bfr[ni], acc[mi][ni], 0, 0, 0);
    }

#pragma unroll
    for (int ni = 0; ni < 4; ++ni) {
        int col = n0 + wn + ni * 16 + l16;
        float bv_ = bias[col];
#pragma unroll
        for (int mi = 0; mi < 4; ++mi)
#pragma unroll
            for (int rr = 0; rr < 4; ++rr) {
                int row = m0 + wm + mi * 16 + q16 * 4 + rr;   // C/D layout (m89/m91)
                C[(size_t)row * PROJ + col] = f2bf(acc[mi][ni][rr] + bv_);
            }
    }
}

// ---------------------------------------------------------------- zero l
__global__ void zero_l_kernel(float* __restrict__ l) {
    l[blockIdx.x * 256 + threadIdx.x] = 0.f;
}

// ---------------------------------------------------------------- score pass
// P[8192][4096] = exp2(c * (qp @ kp_h^T)) bf16, l[row] += rowsums (atomic).
// NEW: 256x256 tile, 512 threads (8 waves, 2M x 4N), BK=32, depth-4 ring
// (4 x 32 KB = 128 KB LDS), counted vmcnt 8/4/0 — per-thread staging identical
// to the proven pv ring (4 gloads/tile). MFMA:ds_read = 32:12 per K-step/wave
// vs 16:8 at 128². Grid 32x16 = 512 blocks = 2 rounds at 1 block/CU.
__global__ __launch_bounds__(512, 2) void score_kernel(
    const u16* __restrict__ qp, const u16* __restrict__ kph,
    u16* __restrict__ P, float* __restrict__ l)
{
    const int m0 = blockIdx.x * 256;
    const int n0 = blockIdx.y * 256;
    __shared__ __align__(16) u16 smem[4 * 16384];   // 128 KB: 4 x (A 16KB + B 16KB)

    const int t = threadIdx.x;
    const int w = t >> 6, ln = t & 63;
    const int q16 = ln >> 4, l16 = ln & 15;
    const int wm2 = w >> 2, wn4 = w & 3;            // wave tile: 128 rows x 64 cols
    const int wrow = wm2 * 128, wcol = wn4 * 64;

    const u16* Abase = qp  + (size_t)m0 * PROJ;
    const u16* Bbase = kph + (size_t)n0 * PROJ;

    floatx4 acc[8][4] = {};

    auto STAGE = [&](int ti) {
        u16* buf = smem + (ti & 3) * 16384;
        stage256x32w(buf,        Abase + ti * 32, PROJ, w, ln);
        stage256x32w(buf + 8192, Bbase + ti * 32, PROJ, w, ln);
    };
    auto COMPUTE = [&](int ti) {
        const u16* As = smem + (ti & 3) * 16384;
        const u16* Bs = As + 8192;
        bf16x8 af[8], bfr[4];
#pragma unroll
        for (int mi = 0; mi < 8; ++mi)
            af[mi] = *(const bf16x8*)(As + (wrow + mi * 16 + l16) * 32 + q16 * 8);
#pragma unroll
        for (int ni = 0; ni < 4; ++ni)
            bfr[ni] = *(const bf16x8*)(Bs + (wcol + ni * 16 + l16) * 32 + q16 * 8);
#pragma unroll
        for (int mi = 0; mi < 8; ++mi)
#pragma unroll
            for (int ni = 0; ni < 4; ++ni)
                acc[mi][ni] = __builtin_amdgcn_mfma_f32_16x16x32_bf16(
                    af[mi], bfr[ni], acc[mi][ni], 0, 0, 0);
    };

    const int NT = PROJ / 32;   // 16 K-steps
    STAGE(0); STAGE(1); STAGE(2);   // 12 loads/thread in flight

    for (int ti = 0; ti < NT - 2; ++ti) {
        VMCNT_WAIT(8);                          // tile-ti loads landed (12->8)
        __builtin_amdgcn_sched_barrier(0);
        __builtin_amdgcn_s_barrier();
        __builtin_amdgcn_sched_barrier(0);      // pin ds_reads below barrier (rule 18)
        if (ti + 3 < NT) STAGE(ti + 3);
        COMPUTE(ti);
    }
    VMCNT_WAIT(4);
    __builtin_amdgcn_sched_barrier(0);
    __builtin_amdgcn_s_barrier();
    __builtin_amdgcn_sched_barrier(0);
    COMPUTE(NT - 2);
    VMCNT_WAIT(0);
    __builtin_amdgcn_sched_barrier(0);
    __builtin_amdgcn_s_barrier();
    __builtin_amdgcn_sched_barrier(0);
    COMPUTE(NT - 1);

    // epilogue: exp2, packed permuted store, fused row-sums -> atomicAdd l
#pragma unroll
    for (int mi = 0; mi < 8; ++mi)
#pragma unroll
        for (int rr = 0; rr < 4; ++rr) {
            int row = m0 + wrow + mi * 16 + q16 * 4 + rr;
            u16* Prow = P + (size_t)row * MHALF + n0 + wcol;
            float tot = 0.f;
            bf16x4 pk;
#pragma unroll
            for (int ni = 0; ni < 4; ++ni) {
                float x = acc[mi][ni][rr] * SCALE_LOG2E_DK;
                x = fminf(fmaxf(x, -30.f), 30.f);
                float p = EXP2(x);
                tot += p;
                pk[ni] = (short)f2bf(p);   // key ni*16+l16 -> phys l16*4+ni
            }
            *(bf16x4*)(Prow + l16 * 4) = pk;   // 8B coalesced
#pragma unroll
            for (int m = 1; m < 16; m <<= 1)
                tot += __shfl_xor(tot, m, 64);
            if (l16 == 0)
                atomicAdd(&l[row], tot);
        }
}

// ---------------------------------------------------------------- PV pass
// Round-5 proven config: 128x128 tile, depth-4 64 KB ring, counted vmcnt
// (8 steady / 4 / 0 peel), grid (64,4,2) default dispatch — 61.6 us measured.
__global__ __launch_bounds__(256) void pv_kernel(
    const u16* __restrict__ P, const u16* __restrict__ vpTh,
    float* __restrict__ Ofull, u16* __restrict__ Opart, int accum)
{
    const int m0 = blockIdx.x * 128;
    const int n0 = blockIdx.y * 128;
    const int kg = blockIdx.z;
    const int kbase = kg * 2048;
    __shared__ __align__(16) u16 smem[4 * 8192];   // 64 KB: ring of 4 x (A 8KB + B 8KB)

    const int t = threadIdx.x;
    const int wv = t >> 6, ln = t & 63;
    const int q16 = ln >> 4, l16 = ln & 15;
    const int wm = (wv & 1) * 64, wn = (wv >> 1) * 64;

    const u16* Abase = P    + (size_t)m0 * MHALF  + kbase;
    const u16* Bbase = vpTh + (size_t)n0 * N_ROWS + kbase;

    floatx4 acc[4][4] = {};

    auto STAGE = [&](int ti) {
        u16* buf = smem + (ti & 3) * 8192;
        stage128x32(buf,        Abase + ti * 32, MHALF,  wv, ln);
        stage128x32(buf + 4096, Bbase + ti * 32, N_ROWS, wv, ln);
    };
    auto COMPUTE = [&](int ti) {
        const u16* As = smem + (ti & 3) * 8192;
        const u16* Bs = As + 4096;
        bf16x8 af[4], bfr[4];
#pragma unroll
        for (int mi = 0; mi < 4; ++mi)
            af[mi] = *(const bf16x8*)(As + (wm + mi * 16 + l16) * 32 + q16 * 8);
#pragma unroll
        for (int ni = 0; ni < 4; ++ni)
            bfr[ni] = *(const bf16x8*)(Bs + (wn + ni * 16 + l16) * 32 + q16 * 8);
#pragma unroll
        for (int mi = 0; mi < 4; ++mi)
#pragma unroll
            for (int ni = 0; ni < 4; ++ni)
                acc[mi][ni] = __builtin_amdgcn_mfma_f32_16x16x32_bf16(
                    af[mi], bfr[ni], acc[mi][ni], 0, 0, 0);
    };

    const int NT = 2048 / 32;   // 64 K-steps
    STAGE(0); STAGE(1); STAGE(2);   // 12 loads/thread in flight

    for (int ti = 0; ti < NT - 2; ++ti) {
        VMCNT_WAIT(8);                          // tile-ti loads landed (12->8)
        __builtin_amdgcn_sched_barrier(0);
        __builtin_amdgcn_s_barrier();           // everyone's landed; reads of ti-1 done
        __builtin_amdgcn_sched_barrier(0);      // pin ds_reads below barrier (rule 18)
        if (ti + 3 < NT) STAGE(ti + 3);         // overwrites slot (ti-1)&3: safe
        COMPUTE(ti);
    }
    VMCNT_WAIT(4);
    __builtin_amdgcn_sched_barrier(0);
    __builtin_amdgcn_s_barrier();
    __builtin_amdgcn_sched_barrier(0);
    COMPUTE(NT - 2);
    VMCNT_WAIT(0);
    __builtin_amdgcn_sched_barrier(0);
    __builtin_amdgcn_s_barrier();
    __builtin_amdgcn_sched_barrier(0);
    COMPUTE(NT - 1);

#pragma unroll
    for (int ni = 0; ni < 4; ++ni) {
        int col = n0 + wn + ni * 16 + l16;
#pragma unroll
        for (int mi = 0; mi < 4; ++mi)
#pragma unroll
            for (int rr = 0; rr < 4; ++rr) {
                int row = m0 + wm + mi * 16 + q16 * 4 + rr;
                size_t o = (size_t)row * PROJ + col;
                float v = acc[mi][ni][rr];
                if (kg == 0) {
                    if (accum) v += Ofull[o];
                    Ofull[o] = v;
                } else {
                    if (accum) v += bf2f(Opart[o]);
                    Opart[o] = f2bf(v);
                }
            }
    }
}

// ---------------------------------------------------------------- scale
__global__ void scale_kernel(float* __restrict__ out, const u16* __restrict__ Opart,
                             const float* __restrict__ l)
{
    int idx = blockIdx.x * 256 + threadIdx.x;   // 8192*512
    int row = idx >> 9;
    out[idx] = (out[idx] + bf2f(Opart[idx])) / l[row];
}

// ---------------------------------------------------------------- launch
extern "C" void kernel_launch(void* const* d_in, const int* in_sizes, int n_in,
                              void* d_out, int out_size, void* d_ws, size_t ws_size,
                              hipStream_t stream)
{
    (void)in_sizes; (void)n_in; (void)out_size;
    if (ws_size < ((size_t)101 << 20)) return;   // visible-fail guard

    const float* q  = (const float*)d_in[0];
    const float* k  = (const float*)d_in[1];
    const float* v  = (const float*)d_in[2];
    const float* Wq = (const float*)d_in[3];
    const float* bq = (const float*)d_in[4];
    const float* Wk = (const float*)d_in[5];
    const float* bk = (const float*)d_in[6];
    const float* Wv = (const float*)d_in[7];
    const float* bv = (const float*)d_in[8];

    char* ws = (char*)d_ws;
    u16* qp    = (u16*)(ws);                        // 8 MB
    u16* kp    = (u16*)(ws + ((size_t)8  << 20));   // 8 MB
    u16* vp    = (u16*)(ws + ((size_t)16 << 20));   // 8 MB (dead after vpT -> reused as Opart)
    u16* vpT   = (u16*)(ws + ((size_t)24 << 20));   // 8 MB
    u16* WqT   = (u16*)(ws + ((size_t)32 << 20));   // 1 MB each (bf16 512x1024)
    u16* WkT   = (u16*)(ws + ((size_t)33 << 20));
    u16* WvT   = (u16*)(ws + ((size_t)34 << 20));
    float* l   = (float*)(ws + ((size_t)35 << 20)); // 32 KB
    u16* P     = (u16*)(ws + ((size_t)36 << 20));   // 64 MB (half-P, reused per half)
    // bf16 copies of q,k,v live in the P region (dead once proj is done; score
    // then overwrites P). 16 MB each.
    u16* qb    = (u16*)(ws + ((size_t)36 << 20));
    u16* kb    = (u16*)(ws + ((size_t)52 << 20));
    u16* vb    = (u16*)(ws + ((size_t)68 << 20));
    u16* Opart = vp;                                // kg1 partial, bf16 8 MB
    float* Ofull = (float*)d_out;                   // kg0 partial accumulates in d_out

    dim3 tb(32, 32);
    transpose_w_kernel<<<dim3(16, 32), tb, 0, stream>>>(Wq, WqT, 1024, 512);
    transpose_w_kernel<<<dim3(16, 32), tb, 0, stream>>>(Wk, WkT, 1024, 512);
    transpose_w_kernel<<<dim3(16, 32), tb, 0, stream>>>(Wv, WvT, 1024, 512);

    convert_bf16_kernel<<<dim3(4096, 3), 256, 0, stream>>>(q, k, v, qb, kb, vb);

    proj_kernel<<<dim3(64, 4, 3), 256, 0, stream>>>(qb, kb, vb, WqT, WkT, WvT,
                                                    bq, bk, bv, qp, kp, vp);

    transpose_kernel<<<dim3(16, 256), tb, 0, stream>>>(vp, vpT, 8192, 512);

    zero_l_kernel<<<32, 256, 0, stream>>>(l);

    // half 0
    score_kernel<<<dim3(32, 16), 512, 0, stream>>>(qp, kp, P, l);
    pv_kernel<<<dim3(64, 4, 2), 256, 0, stream>>>(P, vpT, Ofull, Opart, 0);
    // half 1
    score_kernel<<<dim3(32, 16), 512, 0, stream>>>(qp, kp + (size_t)MHALF * PROJ, P, l);
    pv_kernel<<<dim3(64, 4, 2), 256, 0, stream>>>(P, vpT + MHALF, Ofull, Opart, 1);

    scale_kernel<<<16384, 256, 0, stream>>>(Ofull, Opart, l);
}